// Round 2
// baseline (171.224 us; speedup 1.0000x reference)
//
#include <hip/hip_runtime.h>

// EquivariantLinear: per-head circular 3D cross-correlation on Z_8^3.
// out[b][a][c*8+h] = sum_g x[b][(a+g) mod8 per axis][c*8+h] * W[h][g]
// W[h][g] = sum_s basis[g][s] * kernel[s][h]
//
// Grid: 256 blocks = (b in 0..32) x (a1 in 0..8). Block: 512 threads = channel.
// Per thread: acc[a2][a3] (64 f32). 64 FMA per global load. W in LDS, padded
// stride 516 so the 8 per-head float4 broadcasts cover all 32 banks.
// (Resubmission: rounds 0-1 failed on GPU acquisition, not kernel errors.)

#define BATCH 32
#define NG    8
#define SEQ   512
#define CHAN  512
#define NH    8
#define SDIM  24
#define WPAD  516   // 516 % 32 == 4 -> head h lands on bank group 4h (conflict-free)

__global__ __launch_bounds__(512, 2)
void eqlin_kernel(const float* __restrict__ x,
                  const float* __restrict__ basis,
                  const float* __restrict__ kparam,
                  float* __restrict__ out)
{
    __shared__ float Wlds[NH * WPAD];   // 16.5 KiB

    const int tid = threadIdx.x;
    const int b   = blockIdx.x >> 3;
    const int a1  = blockIdx.x & 7;
    const int ch  = tid;         // 0..511, channel = c*8 + h
    const int h   = ch & 7;

    // ---- stage W[h][g] = sum_s basis[g][s] * kparam[s][h] into LDS ----
    // thread g = tid computes all 8 heads (cost ~98K FMA/block, negligible)
    {
        float wacc[NH];
#pragma unroll
        for (int hh = 0; hh < NH; ++hh) wacc[hh] = 0.0f;
        const float* bg = basis + tid * SDIM;
#pragma unroll
        for (int s = 0; s < SDIM; ++s) {
            const float bv = bg[s];
#pragma unroll
            for (int hh = 0; hh < NH; ++hh)
                wacc[hh] += bv * kparam[s * NH + hh];   // kparam uniform -> s_load
        }
#pragma unroll
        for (int hh = 0; hh < NH; ++hh)
            Wlds[hh * WPAD + tid] = wacc[hh];
    }
    __syncthreads();

    float acc[8][8];   // [a2][a3]
#pragma unroll
    for (int i = 0; i < 8; ++i)
#pragma unroll
        for (int j = 0; j < 8; ++j) acc[i][j] = 0.0f;

    const float* xb = x + (size_t)b * (SEQ * CHAN) + ch;
    const float* wh = &Wlds[h * WPAD];

#pragma unroll 1
    for (int g1 = 0; g1 < 8; ++g1) {
        const int p1 = (a1 + g1) & 7;
        const float* wg1 = wh + g1 * 64;
#pragma unroll 2
        for (int p2 = 0; p2 < 8; ++p2) {
            // 8 coalesced loads: x[b][p1][p2][p3=0..7][ch]
            const float* xp = xb + (p1 * 64 + p2 * 8) * CHAN;
            float xr[8];
#pragma unroll
            for (int k = 0; k < 8; ++k) xr[k] = xp[k * CHAN];
#pragma unroll
            for (int a2 = 0; a2 < 8; ++a2) {
                const int g2 = (p2 - a2) & 7;
                // 8 taps w[h][g1][g2][g3], 16B-aligned, bank-conflict-free broadcast
                const float4 w0 = *(const float4*)(wg1 + g2 * 8);
                const float4 w1 = *(const float4*)(wg1 + g2 * 8 + 4);
                const float wr[8] = {w0.x, w0.y, w0.z, w0.w,
                                     w1.x, w1.y, w1.z, w1.w};
#pragma unroll
                for (int a3 = 0; a3 < 8; ++a3) {
#pragma unroll
                    for (int g3 = 0; g3 < 8; ++g3)
                        acc[a2][a3] += xr[(a3 + g3) & 7] * wr[g3];
                }
            }
        }
    }

    // ---- coalesced epilogue: out[b][a1][a2][a3][ch] ----
    float* ob = out + (size_t)b * (SEQ * CHAN) + (a1 * 64) * CHAN + ch;
#pragma unroll
    for (int a2 = 0; a2 < 8; ++a2)
#pragma unroll
        for (int a3 = 0; a3 < 8; ++a3)
            ob[(a2 * 8 + a3) * CHAN] = acc[a2][a3];
}

extern "C" void kernel_launch(void* const* d_in, const int* in_sizes, int n_in,
                              void* d_out, int out_size, void* d_ws, size_t ws_size,
                              hipStream_t stream)
{
    const float* x      = (const float*)d_in[0];   // [32][512][512] f32
    const float* basis  = (const float*)d_in[1];   // [512][24]      f32
    const float* kparam = (const float*)d_in[2];   // [24][8]        f32
    float* out          = (float*)d_out;           // [32][512][512] f32

    hipLaunchKernelGGL(eqlin_kernel, dim3(BATCH * NG), dim3(512), 0, stream,
                       x, basis, kparam, out);
}

// Round 3
// 98.132 us; speedup vs baseline: 1.7448x; 1.7448x over previous
//
#include <hip/hip_runtime.h>

// EquivariantLinear = per-head circular correlation on Z_8^3:
//   out[b][a][c*8+h] = sum_g x[b][(a+g) mod8 per axis][c*8+h] * W[h][g]
//   W[h][g] = sum_s basis[g][s] * kernel[s][h]
// FFT route: out = IDFT( DFT(x) * V ),  V[h][f] = conj(DFT(W_h))[f] / 512.
// 8-point DFT twiddles are {±1, ±i, (±1±i)/sqrt2} -> almost multiply-free.
// Direct-conv = 8.6 GF (55us VALU floor, measured 113us). FFT = ~0.35 GF ->
// memory-bound: 67 MB HBM ~ 11us floor.

#define S2C 0.70710678118654752f
#define SIGSTRIDE 577   // per-signal LDS stride (8*8*9 pad + 1): breaks bank aliasing

// ---------------------------------------------------------------- DFT-8 in-place
template <bool INV>
__device__ __forceinline__ void dft8(float* R, float* I)
{
    // DIF radix-2; forward twiddles w = e^{-2pi i/8}; inverse = conjugate.
    float t0r = R[0] + R[4], t0i = I[0] + I[4];
    float t1r = R[1] + R[5], t1i = I[1] + I[5];
    float t2r = R[2] + R[6], t2i = I[2] + I[6];
    float t3r = R[3] + R[7], t3i = I[3] + I[7];
    float b0r = R[0] - R[4], b0i = I[0] - I[4];
    float d1r = R[1] - R[5], d1i = I[1] - I[5];
    float d2r = R[2] - R[6], d2i = I[2] - I[6];
    float d3r = R[3] - R[7], d3i = I[3] - I[7];
    float b1r, b1i, b2r, b2i, b3r, b3i;
    if (!INV) {            // *w1=(1-i)/s2, *(-i), *w3=(-1-i)/s2
        b1r = (d1r + d1i) * S2C;  b1i = (d1i - d1r) * S2C;
        b2r = d2i;                b2i = -d2r;
        b3r = (d3i - d3r) * S2C;  b3i = -(d3r + d3i) * S2C;
    } else {               // conjugates: (1+i)/s2, (+i), (-1+i)/s2
        b1r = (d1r - d1i) * S2C;  b1i = (d1i + d1r) * S2C;
        b2r = -d2i;               b2i = d2r;
        b3r = -(d3r + d3i) * S2C; b3i = (d3r - d3i) * S2C;
    }
    // even half: DFT4 of t -> X0,X2,X4,X6
    float u0r = t0r + t2r, u0i = t0i + t2i;
    float u1r = t1r + t3r, u1i = t1i + t3i;
    float u2r = t0r - t2r, u2i = t0i - t2i;
    float e3r = t1r - t3r, e3i = t1i - t3i;
    float u3r, u3i;
    if (!INV) { u3r = e3i;  u3i = -e3r; }
    else      { u3r = -e3i; u3i = e3r;  }
    R[0] = u0r + u1r; I[0] = u0i + u1i;
    R[4] = u0r - u1r; I[4] = u0i - u1i;
    R[2] = u2r + u3r; I[2] = u2i + u3i;
    R[6] = u2r - u3r; I[6] = u2i - u3i;
    // odd half: DFT4 of b -> X1,X3,X5,X7
    float v0r = b0r + b2r, v0i = b0i + b2i;
    float v1r = b1r + b3r, v1i = b1i + b3i;
    float v2r = b0r - b2r, v2i = b0i - b2i;
    float w3r = b1r - b3r, w3i = b1i - b3i;
    float v3r, v3i;
    if (!INV) { v3r = w3i;  v3i = -w3r; }
    else      { v3r = -w3i; v3i = w3r;  }
    R[1] = v0r + v1r; I[1] = v0i + v1i;
    R[5] = v0r - v1r; I[5] = v0i - v1i;
    R[3] = v2r + v3r; I[3] = v2i + v3i;
    R[7] = v2r - v3r; I[7] = v2i - v3i;
}

// ---------------------------------------------------------------- prep kernel
// V[h*512 + f] = (1/512) * sum_g W[h][g] * e^{+2pi i (f1g1+f2g2+f3g3)/8}
__device__ const float CTAB8[8] = {1.f, S2C, 0.f, -S2C, -1.f, -S2C, 0.f, S2C};
__device__ const float STAB8[8] = {0.f, S2C, 1.f, S2C, 0.f, -S2C, -1.f, -S2C};

__global__ __launch_bounds__(256)
void eqfft_prep(const float* __restrict__ basis,
                const float* __restrict__ kparam,
                float2* __restrict__ V)
{
    __shared__ float Wl[512];      // W for this block's head, layout [(g2*8+g3)][g1]
    __shared__ float CT[8], ST[8];
    const int tid = threadIdx.x;
    const int blk = blockIdx.x;    // 128 blocks: h = blk>>4, f-base = (blk&15)*32
    const int h   = blk >> 4;
    if (tid < 8) { CT[tid] = CTAB8[tid]; ST[tid] = STAB8[tid]; }
    #pragma unroll
    for (int t = 0; t < 2; ++t) {
        const int g = tid * 2 + t;
        const float* bp = basis + g * 24;
        float acc = 0.f;
        #pragma unroll
        for (int s = 0; s < 24; ++s) acc += bp[s] * kparam[s * 8 + h];
        Wl[(g & 63) * 8 + (g >> 6)] = acc;   // transpose: g1 innermost -> bank-free
    }
    __syncthreads();
    const int f  = (blk & 15) * 32 + (tid >> 3);
    const int g1 = tid & 7;
    const int f1 = f >> 6, f2 = (f >> 3) & 7, f3 = f & 7;
    const int kb = (f1 * g1) & 7;
    float pr = 0.f, pi = 0.f;
    for (int g2 = 0; g2 < 8; ++g2) {
        const int k2 = kb + f2 * g2;
        const float* wrow = &Wl[g2 * 64 + g1];
        #pragma unroll
        for (int g3 = 0; g3 < 8; ++g3) {
            const int k = (k2 + f3 * g3) & 7;
            const float w = wrow[g3 * 8];
            pr += w * CT[k];
            pi += w * ST[k];
        }
    }
    pr += __shfl_xor(pr, 1); pi += __shfl_xor(pi, 1);
    pr += __shfl_xor(pr, 2); pi += __shfl_xor(pi, 2);
    pr += __shfl_xor(pr, 4); pi += __shfl_xor(pi, 4);
    if (g1 == 0)
        V[h * 512 + f] = make_float2(pr * (1.f / 512.f), pi * (1.f / 512.f));
}

// ---------------------------------------------------------------- main kernel
// 2048 WGs x 512 thr. WG = (b, 8-channel tile) = 8 signals; wave w owns signal w.
// LDS complex [8 sig][p1][p2][p3] padded: idx = s*577 + p1*72 + p2*9 + p3.
__global__ __launch_bounds__(512, 6)
void eqfft_main(const float* __restrict__ x,
                const float2* __restrict__ V,
                float* __restrict__ out)
{
    __shared__ float reA[8 * SIGSTRIDE];
    __shared__ float imA[8 * SIGSTRIDE];

    const int tid  = threadIdx.x;
    const int bid  = blockIdx.x;
    const int L    = (bid & 7) * 256 + (bid >> 3);  // XCD-chunked swizzle (2048%8==0)
    const int b    = L >> 6;
    const int ch0  = (L & 63) * 8;
    const int wid  = tid >> 6;
    const int lane = tid & 63;

    const float* xb = x  + (size_t)b * 262144 + ch0;
    float*       ob = out + (size_t)b * 262144 + ch0;

    // stage-in: 8 ch x 512 p = 1024 float4, 2 per thread (coalesced 32B/row)
    #pragma unroll
    for (int i = 0; i < 2; ++i) {
        const int v  = i * 512 + tid;
        const int p  = v >> 1;
        const int c4 = (v & 1) * 4;
        const float4 d = *(const float4*)(xb + p * 512 + c4);
        const int base = (p >> 6) * 72 + ((p >> 3) & 7) * 9 + (p & 7);
        reA[(c4 + 0) * SIGSTRIDE + base] = d.x;
        reA[(c4 + 1) * SIGSTRIDE + base] = d.y;
        reA[(c4 + 2) * SIGSTRIDE + base] = d.z;
        reA[(c4 + 3) * SIGSTRIDE + base] = d.w;
    }
    __syncthreads();

    // pass 3 fwd (along p3, stride 1, real input)
    {
        const int base = wid * SIGSTRIDE + (lane >> 3) * 72 + (lane & 7) * 9;
        float R[8], I[8];
        #pragma unroll
        for (int j = 0; j < 8; ++j) { R[j] = reA[base + j]; I[j] = 0.f; }
        dft8<false>(R, I);
        #pragma unroll
        for (int j = 0; j < 8; ++j) { reA[base + j] = R[j]; imA[base + j] = I[j]; }
    }
    __syncthreads();

    // pass 2 fwd (along p2, stride 9)
    {
        const int base = wid * SIGSTRIDE + (lane >> 3) * 72 + (lane & 7);
        float R[8], I[8];
        #pragma unroll
        for (int j = 0; j < 8; ++j) { R[j] = reA[base + j * 9]; I[j] = imA[base + j * 9]; }
        dft8<false>(R, I);
        #pragma unroll
        for (int j = 0; j < 8; ++j) { reA[base + j * 9] = R[j]; imA[base + j * 9] = I[j]; }
    }
    __syncthreads();

    // pass 1 fwd + pointwise V + pass 1 inv (along p1, stride 72) — fused
    {
        const int p2 = lane >> 3, p3 = lane & 7;
        const int base = wid * SIGSTRIDE + p2 * 9 + p3;
        const float2* vp = V + (wid << 9) + (p2 << 3) + p3;   // h == wid (ch0%8==0)
        float R[8], I[8];
        #pragma unroll
        for (int j = 0; j < 8; ++j) { R[j] = reA[base + j * 72]; I[j] = imA[base + j * 72]; }
        dft8<false>(R, I);
        #pragma unroll
        for (int j = 0; j < 8; ++j) {
            const float2 v = vp[j << 6];       // V[h][f1=j][f2=p2][f3=p3]
            const float nr = R[j] * v.x - I[j] * v.y;
            I[j] = R[j] * v.y + I[j] * v.x;
            R[j] = nr;
        }
        dft8<true>(R, I);
        #pragma unroll
        for (int j = 0; j < 8; ++j) { reA[base + j * 72] = R[j]; imA[base + j * 72] = I[j]; }
    }
    __syncthreads();

    // pass 2 inv (along p2, stride 9)
    {
        const int base = wid * SIGSTRIDE + (lane >> 3) * 72 + (lane & 7);
        float R[8], I[8];
        #pragma unroll
        for (int j = 0; j < 8; ++j) { R[j] = reA[base + j * 9]; I[j] = imA[base + j * 9]; }
        dft8<true>(R, I);
        #pragma unroll
        for (int j = 0; j < 8; ++j) { reA[base + j * 9] = R[j]; imA[base + j * 9] = I[j]; }
    }
    __syncthreads();

    // pass 3 inv (along p3, stride 1) — result is real; write re only
    {
        const int base = wid * SIGSTRIDE + (lane >> 3) * 72 + (lane & 7) * 9;
        float R[8], I[8];
        #pragma unroll
        for (int j = 0; j < 8; ++j) { R[j] = reA[base + j]; I[j] = imA[base + j]; }
        dft8<true>(R, I);
        #pragma unroll
        for (int j = 0; j < 8; ++j) { reA[base + j] = R[j]; }
    }
    __syncthreads();

    // copy-out (coalesced float4)
    #pragma unroll
    for (int i = 0; i < 2; ++i) {
        const int v  = i * 512 + tid;
        const int p  = v >> 1;
        const int c4 = (v & 1) * 4;
        const int base = (p >> 6) * 72 + ((p >> 3) & 7) * 9 + (p & 7);
        float4 d;
        d.x = reA[(c4 + 0) * SIGSTRIDE + base];
        d.y = reA[(c4 + 1) * SIGSTRIDE + base];
        d.z = reA[(c4 + 2) * SIGSTRIDE + base];
        d.w = reA[(c4 + 3) * SIGSTRIDE + base];
        *(float4*)(ob + p * 512 + c4) = d;
    }
}

extern "C" void kernel_launch(void* const* d_in, const int* in_sizes, int n_in,
                              void* d_out, int out_size, void* d_ws, size_t ws_size,
                              hipStream_t stream)
{
    const float* x      = (const float*)d_in[0];   // [32][512][512]
    const float* basis  = (const float*)d_in[1];   // [512][24]
    const float* kparam = (const float*)d_in[2];   // [24][8]
    float* out          = (float*)d_out;
    float2* V           = (float2*)d_ws;           // 8*512*8B = 32 KB scratch

    hipLaunchKernelGGL(eqfft_prep, dim3(128),  dim3(256), 0, stream, basis, kparam, V);
    hipLaunchKernelGGL(eqfft_main, dim3(2048), dim3(512), 0, stream, x, V, out);
}